// Round 2
// baseline (565.962 us; speedup 1.0000x reference)
//
#include <hip/hip_runtime.h>

#define B_ 2
#define S_ 2048
#define D_ 1024      // D_IN = DKQ = DV = E
#define H_ 16
#define HD_ 64       // DV / H
#define SPLITS 2
#define TSPAN (S_/SPLITS)   // 1024 keys per split-block

typedef _Float16 f16;
typedef _Float16 half8 __attribute__((ext_vector_type(8)));
typedef float float4_ __attribute__((ext_vector_type(4)));

#define N_HS (B_*S_*D_)   // 4194304
#define N_W  (D_*D_)      // 1048576
#define N_MIX (H_*D_)     // 16384

// ---------------- convert fp32 -> fp16 (mixing scaled by 1/sqrt(64)) ----------------
__global__ __launch_bounds__(256) void convert_kernel(
    const float* __restrict__ hs, const float* __restrict__ wq,
    const float* __restrict__ wk, const float* __restrict__ wv,
    const float* __restrict__ mix,
    f16* __restrict__ hs16, f16* __restrict__ wq16, f16* __restrict__ wk16,
    f16* __restrict__ wv16, f16* __restrict__ mix16)
{
  const int total4 = (N_HS + 3*N_W + N_MIX) / 4;
  for (int i4 = blockIdx.x*blockDim.x + threadIdx.x; i4 < total4;
       i4 += gridDim.x*blockDim.x) {
    int i = i4*4;
    const float* src; f16* dst; float scale = 1.0f; int off;
    if (i < N_HS)            { src=hs;  dst=hs16;  off=i; }
    else if (i < N_HS+N_W)   { src=wq;  dst=wq16;  off=i-N_HS; }
    else if (i < N_HS+2*N_W) { src=wk;  dst=wk16;  off=i-N_HS-N_W; }
    else if (i < N_HS+3*N_W) { src=wv;  dst=wv16;  off=i-N_HS-2*N_W; }
    else                     { src=mix; dst=mix16; off=i-N_HS-3*N_W; scale=0.125f; }
    float4 v = *(const float4*)(src+off);
    dst[off]   = (f16)(v.x*scale);
    dst[off+1] = (f16)(v.y*scale);
    dst[off+2] = (f16)(v.z*scale);
    dst[off+3] = (f16)(v.w*scale);
  }
}

// ---------------- QKV GEMM: C[4096,1024] = hs16 @ W^T (NT, fp16 MFMA) ----------------
// z==2 (V) adds bias and writes TRANSPOSED: vT[b][ch][t]  (so attn needs no LDS transpose)
#define BM 128
#define BN 128
#define BK 64
#define LDA 72   // BK + 8 pad: 144B row stride = 16B aligned, 2-way bank alias (free)

__global__ __launch_bounds__(256, 2) void qkv_kernel(
    const f16* __restrict__ hs16, const f16* __restrict__ w16base,
    const float* __restrict__ bv,
    f16* __restrict__ q16, f16* __restrict__ k16, f16* __restrict__ vT)
{
  const int z = blockIdx.z;
  const f16* W = w16base + (size_t)z * N_W;
  f16* out = (z==0) ? q16 : k16;
  const int mt = blockIdx.y, nt = blockIdx.x;
  const int tid = threadIdx.x;
  const int lane = tid & 63, wid = tid >> 6;
  const int wm = wid >> 1, wn = wid & 1;
  const int quad = lane >> 4, l16 = lane & 15;

  __shared__ __align__(16) f16 As[BM][LDA];
  __shared__ __align__(16) f16 Bs[BN][LDA];

  float4_ acc[4][4];
#pragma unroll
  for (int i=0;i<4;i++)
#pragma unroll
    for (int j=0;j<4;j++) acc[i][j] = (float4_)0.0f;

  const int row0 = mt*BM;
  const int col0 = nt*BN;

  for (int ko = 0; ko < D_; ko += BK) {
#pragma unroll
    for (int it=0; it<4; it++) {
      int c = it*256 + tid;
      int r = c >> 3, c8 = (c & 7)*8;
      *(half8*)&As[r][c8] = *(const half8*)&hs16[(size_t)(row0+r)*D_ + ko + c8];
      *(half8*)&Bs[r][c8] = *(const half8*)&W[(size_t)(col0+r)*D_ + ko + c8];
    }
    __syncthreads();
#pragma unroll
    for (int kk=0; kk<BK; kk+=32) {
      half8 a[4], b[4];
#pragma unroll
      for (int i=0;i<4;i++) a[i] = *(const half8*)&As[wm*64+i*16+l16][kk+quad*8];
#pragma unroll
      for (int j=0;j<4;j++) b[j] = *(const half8*)&Bs[wn*64+j*16+l16][kk+quad*8];
#pragma unroll
      for (int i=0;i<4;i++)
#pragma unroll
        for (int j=0;j<4;j++)
          acc[i][j] = __builtin_amdgcn_mfma_f32_16x16x32_f16(a[i], b[j], acc[i][j], 0,0,0);
    }
    __syncthreads();
  }
#pragma unroll
  for (int i=0;i<4;i++) {
#pragma unroll
    for (int j=0;j<4;j++) {
      int colg = col0 + wn*64 + j*16 + l16;
      float bias = (z==2) ? bv[colg] : 0.0f;
#pragma unroll
      for (int r=0;r<4;r++) {
        int rowg = row0 + wm*64 + i*16 + quad*4 + r;
        f16 val = (f16)(acc[i][j][r] + bias);
        if (z == 2) {
          int bb = rowg >> 11, ss = rowg & (S_-1);
          vT[((size_t)bb*D_ + colg)*S_ + ss] = val;
        } else {
          out[(size_t)rowg*D_ + colg] = val;
        }
      }
    }
  }
}

// ---------------- flash attention (split-t): per (b, split, h, 128-query tile) ----------------
#define TQ 128
#define TK 128
#define LDP 136  // TK + 8 pad: 272B stride = 16B aligned, 2-way alias

__global__ __launch_bounds__(256, 4) void attn_kernel(
    const f16* __restrict__ q16, const f16* __restrict__ k16,
    const f16* __restrict__ vT, const f16* __restrict__ mix16,
    float* __restrict__ po, float* __restrict__ m_part, float* __restrict__ l_part)
{
  const int zz = blockIdx.z;
  const int b = zz >> 1, split = zz & 1;
  const int h = blockIdx.y;
  const int s0 = blockIdx.x * TQ;
  const int tid = threadIdx.x;
  const int lane = tid & 63, wid = tid >> 6;
  const int wm = wid >> 1, wn = wid & 1;
  const int quad = lane >> 4, l16 = lane & 15;

  __shared__ __align__(16) union {
    struct { f16 q[TQ][LDA]; f16 k[TK][LDA]; } s1;   // 36864 B
    f16 P[TQ][LDP];                                  // 34816 B
  } u;
  __shared__ float m_s[TQ], alpha_s[TQ], l_s[TQ], red[2][TQ];

  if (tid < TQ) { m_s[tid] = -1e30f; l_s[tid] = 0.0f; }

  float4_ o_acc[4][2];
#pragma unroll
  for (int i=0;i<4;i++)
#pragma unroll
    for (int j=0;j<2;j++) o_acc[i][j] = (float4_)0.0f;

  const f16* qbase = q16 + (size_t)(b*S_ + s0)*D_;
  const f16* kbase = k16 + (size_t)b*S_*D_;
  const f16* mrow  = mix16 + h*D_;
  const f16* vTb   = vT + (size_t)(b*D_ + h*HD_)*S_;

  for (int t0 = split*TSPAN; t0 < split*TSPAN + TSPAN; t0 += TK) {
    // ---- S = (q*mix) @ k^T over K=1024 ----
    float4_ sacc[4][4];
#pragma unroll
    for (int i=0;i<4;i++)
#pragma unroll
      for (int j=0;j<4;j++) sacc[i][j] = (float4_)0.0f;

    for (int ko = 0; ko < D_; ko += BK) {
#pragma unroll
      for (int it=0; it<4; it++) {
        int c = it*256 + tid;
        int r = c >> 3, c8 = (c & 7)*8;
        half8 qv = *(const half8*)&qbase[(size_t)r*D_ + ko + c8];
        half8 mv = *(const half8*)&mrow[ko + c8];
        *(half8*)&u.s1.q[r][c8] = qv * mv;
        *(half8*)&u.s1.k[r][c8] = *(const half8*)&kbase[(size_t)(t0+r)*D_ + ko + c8];
      }
      __syncthreads();
#pragma unroll
      for (int kk=0; kk<BK; kk+=32) {
        half8 a[4], bf[4];
#pragma unroll
        for (int i=0;i<4;i++) a[i]  = *(const half8*)&u.s1.q[wm*64+i*16+l16][kk+quad*8];
#pragma unroll
        for (int j=0;j<4;j++) bf[j] = *(const half8*)&u.s1.k[wn*64+j*16+l16][kk+quad*8];
#pragma unroll
        for (int i=0;i<4;i++)
#pragma unroll
          for (int j=0;j<4;j++)
            sacc[i][j] = __builtin_amdgcn_mfma_f32_16x16x32_f16(a[i], bf[j], sacc[i][j], 0,0,0);
      }
      __syncthreads();
    }

    // ---- online softmax: row stats. lane holds 16 rows; row = wm*64+i*16+quad*4+r
    float rmax[16];
#pragma unroll
    for (int i=0;i<4;i++)
#pragma unroll
      for (int r=0;r<4;r++) {
        float v0 = fmaxf(sacc[i][0][r], sacc[i][1][r]);
        float v1 = fmaxf(sacc[i][2][r], sacc[i][3][r]);
        rmax[i*4+r] = fmaxf(v0, v1);
      }
#pragma unroll
    for (int d=1; d<16; d<<=1)
#pragma unroll
      for (int t=0;t<16;t++) rmax[t] = fmaxf(rmax[t], __shfl_xor(rmax[t], d));
    if (l16 == 0) {
#pragma unroll
      for (int i=0;i<4;i++)
#pragma unroll
        for (int r=0;r<4;r++)
          red[wn][wm*64+i*16+quad*4+r] = rmax[i*4+r];
    }
    __syncthreads();
    if (tid < TQ) {
      float mold = m_s[tid];
      float mnew = fmaxf(mold, fmaxf(red[0][tid], red[1][tid]));
      m_s[tid] = mnew;
      alpha_s[tid] = __expf(mold - mnew);
    }
    __syncthreads();

    // ---- P = exp(S - m), rowsum, write P fp16 to LDS; rescale O ----
    float mloc[16], aloc[16], rsum[16];
#pragma unroll
    for (int i=0;i<4;i++)
#pragma unroll
      for (int r=0;r<4;r++) {
        int row = wm*64+i*16+quad*4+r;
        mloc[i*4+r] = m_s[row];
        aloc[i*4+r] = alpha_s[row];
        rsum[i*4+r] = 0.0f;
      }
#pragma unroll
    for (int i=0;i<4;i++)
#pragma unroll
      for (int j=0;j<4;j++)
#pragma unroll
        for (int r=0;r<4;r++) {
          float p = __expf(sacc[i][j][r] - mloc[i*4+r]);
          rsum[i*4+r] += p;
          u.P[wm*64+i*16+quad*4+r][wn*64+j*16+l16] = (f16)p;
        }
#pragma unroll
    for (int d=1; d<16; d<<=1)
#pragma unroll
      for (int t=0;t<16;t++) rsum[t] += __shfl_xor(rsum[t], d);
    if (l16 == 0) {
#pragma unroll
      for (int i=0;i<4;i++)
#pragma unroll
        for (int r=0;r<4;r++)
          red[wn][wm*64+i*16+quad*4+r] = rsum[i*4+r];
    }
    // rescale O accumulators by alpha
#pragma unroll
    for (int i=0;i<4;i++)
#pragma unroll
      for (int j=0;j<2;j++)
#pragma unroll
        for (int r=0;r<4;r++) o_acc[i][j][r] *= aloc[i*4+r];

    // prefetch PV B-fragments from global vT (latency hides under barrier)
    half8 vb[8];
#pragma unroll
    for (int ki=0; ki<4; ki++)
#pragma unroll
      for (int j=0; j<2; j++) {
        int ch = wn*32 + j*16 + l16;
        vb[ki*2+j] = *(const half8*)&vTb[(size_t)ch*S_ + t0 + ki*32 + quad*8];
      }

    __syncthreads();
    if (tid < TQ) l_s[tid] = alpha_s[tid]*l_s[tid] + red[0][tid] + red[1][tid];

    // ---- O += P @ V ----
#pragma unroll
    for (int ki=0; ki<4; ki++) {
      half8 pa[4];
#pragma unroll
      for (int i=0;i<4;i++) pa[i] = *(const half8*)&u.P[wm*64+i*16+l16][ki*32+quad*8];
#pragma unroll
      for (int i=0;i<4;i++)
#pragma unroll
        for (int j=0;j<2;j++)
          o_acc[i][j] = __builtin_amdgcn_mfma_f32_16x16x32_f16(pa[i], vb[ki*2+j], o_acc[i][j], 0,0,0);
    }
    __syncthreads();
  }

  // ---- epilogue: unnormalized partial O (fp32) + per-row m,l ----
  float* po_b = po + ((size_t)(split*B_ + b)*S_ + s0)*D_;
#pragma unroll
  for (int i=0;i<4;i++) {
#pragma unroll
    for (int j=0;j<2;j++) {
      int colg = h*HD_ + wn*32 + j*16 + l16;
#pragma unroll
      for (int r=0;r<4;r++) {
        int row = wm*64 + i*16 + quad*4 + r;
        po_b[(size_t)row*D_ + colg] = o_acc[i][j][r];
      }
    }
  }
  if (tid < TQ) {
    size_t sb = ((size_t)(split*B_ + b)*H_ + h)*S_ + s0 + tid;
    m_part[sb] = m_s[tid];
    l_part[sb] = l_s[tid];
  }
}

// ---------------- combine: merge the 2 splits ----------------
__global__ __launch_bounds__(256) void combine_kernel(
    const float* __restrict__ po, const float* __restrict__ m_part,
    const float* __restrict__ l_part, float* __restrict__ out)
{
  int t = blockIdx.x*256 + threadIdx.x;    // one float4 per thread
  int e = t*4;
  int d = e & (D_-1);
  int s = (e >> 10) & (S_-1);
  int b = e >> 21;
  int h = d >> 6;
  size_t sb = ((size_t)b*H_ + h)*S_ + s;
  const size_t sstr = (size_t)B_*H_*S_;
  float m0 = m_part[sb], m1 = m_part[sb + sstr];
  float l0 = l_part[sb], l1 = l_part[sb + sstr];
  float mm = fmaxf(m0, m1);
  float w0 = __expf(m0 - mm), w1 = __expf(m1 - mm);
  float inv = 1.0f / (w0*l0 + w1*l1);
  w0 *= inv; w1 *= inv;
  const size_t ostr4 = (size_t)B_*S_*D_/4;
  float4 o0 = ((const float4*)po)[t];
  float4 o1 = ((const float4*)po)[t + ostr4];
  float4 r;
  r.x = o0.x*w0 + o1.x*w1;
  r.y = o0.y*w0 + o1.y*w1;
  r.z = o0.z*w0 + o1.z*w1;
  r.w = o0.w*w0 + o1.w*w1;
  ((float4*)out)[t] = r;
}

// ---------------- launch ----------------
extern "C" void kernel_launch(void* const* d_in, const int* in_sizes, int n_in,
                              void* d_out, int out_size, void* d_ws, size_t ws_size,
                              hipStream_t stream) {
  (void)in_sizes; (void)n_in; (void)out_size; (void)ws_size;
  const float* hs  = (const float*)d_in[0];
  const float* Wq  = (const float*)d_in[1];
  const float* Wk  = (const float*)d_in[2];
  const float* Wv  = (const float*)d_in[3];
  const float* bv  = (const float*)d_in[4];
  const float* mix = (const float*)d_in[5];
  float* out = (float*)d_out;

  char* ws = (char*)d_ws;
  // po (64 MB) aliases hs16/w16: convert+qkv finish before attn writes po.
  float* po     = (float*)(ws);                       // 67108864 B
  float* m_part = (float*)(ws + 67108864);            // 524288 B
  float* l_part = (float*)(ws + 67633152);            // 524288 B
  f16*   mix16  = (f16*)(ws + 68157440);              // 32768 B
  f16*   q16    = (f16*)(ws + 68190208);              // 8388608 B
  f16*   k16    = (f16*)(ws + 76578816);              // 8388608 B
  f16*   vT     = (f16*)(ws + 84967424);              // 8388608 B
  f16*   hs16   = (f16*)(ws);                         // alias (dead after qkv)
  f16*   w16    = (f16*)(ws + 8388608);               // alias (dead after qkv)

  convert_kernel<<<2048, 256, 0, stream>>>(hs, Wq, Wk, Wv, mix,
                                           hs16, w16, w16+N_W, w16+2*N_W, mix16);
  qkv_kernel<<<dim3(D_/BN, (B_*S_)/BM, 3), 256, 0, stream>>>(
      hs16, w16, bv, q16, k16, vT);
  attn_kernel<<<dim3(S_/TQ, H_, SPLITS*B_), 256, 0, stream>>>(
      q16, k16, vT, mix16, po, m_part, l_part);
  combine_kernel<<<(B_*S_*D_/4)/256, 256, 0, stream>>>(po, m_part, l_part, out);
}

// Round 3
// 503.744 us; speedup vs baseline: 1.1235x; 1.1235x over previous
//
#include <hip/hip_runtime.h>

#define B_ 2
#define S_ 2048
#define D_ 1024      // D_IN = DKQ = DV = E
#define H_ 16
#define HD_ 64       // DV / H

typedef _Float16 f16;
typedef _Float16 half8 __attribute__((ext_vector_type(8)));
typedef float float4_ __attribute__((ext_vector_type(4)));

#define N_HS (B_*S_*D_)   // 4194304
#define N_W  (D_*D_)      // 1048576
#define N_MIX (H_*D_)     // 16384

__device__ __forceinline__ void gl_lds16(const f16* g, const f16* l) {
  __builtin_amdgcn_global_load_lds(
      (const __attribute__((address_space(1))) void*)g,
      (__attribute__((address_space(3))) void*)l, 16, 0, 0);
}

// ---------------- convert fp32 -> fp16 (mixing scaled by 1/sqrt(64)) ----------------
__global__ __launch_bounds__(256) void convert_kernel(
    const float* __restrict__ hs, const float* __restrict__ wq,
    const float* __restrict__ wk, const float* __restrict__ wv,
    const float* __restrict__ mix,
    f16* __restrict__ hs16, f16* __restrict__ wq16, f16* __restrict__ wk16,
    f16* __restrict__ wv16, f16* __restrict__ mix16)
{
  const int total4 = (N_HS + 3*N_W + N_MIX) / 4;
  for (int i4 = blockIdx.x*blockDim.x + threadIdx.x; i4 < total4;
       i4 += gridDim.x*blockDim.x) {
    int i = i4*4;
    const float* src; f16* dst; float scale = 1.0f; int off;
    if (i < N_HS)            { src=hs;  dst=hs16;  off=i; }
    else if (i < N_HS+N_W)   { src=wq;  dst=wq16;  off=i-N_HS; }
    else if (i < N_HS+2*N_W) { src=wk;  dst=wk16;  off=i-N_HS-N_W; }
    else if (i < N_HS+3*N_W) { src=wv;  dst=wv16;  off=i-N_HS-2*N_W; }
    else                     { src=mix; dst=mix16; off=i-N_HS-3*N_W; scale=0.125f; }
    float4 v = *(const float4*)(src+off);
    dst[off]   = (f16)(v.x*scale);
    dst[off+1] = (f16)(v.y*scale);
    dst[off+2] = (f16)(v.z*scale);
    dst[off+3] = (f16)(v.w*scale);
  }
}

// ---------------- QKV GEMM: C[4096,1024] = hs16 @ W^T (NT, fp16 MFMA) ----------------
// z==2 (V) adds bias and writes TRANSPOSED: vT[b][ch][t]
#define BM 128
#define BN 128
#define BK 64
#define LDA 72   // BK + 8 pad

__global__ __launch_bounds__(256, 2) void qkv_kernel(
    const f16* __restrict__ hs16, const f16* __restrict__ w16base,
    const float* __restrict__ bv,
    f16* __restrict__ q16, f16* __restrict__ k16, f16* __restrict__ vT)
{
  const int z = blockIdx.z;
  const f16* W = w16base + (size_t)z * N_W;
  f16* out = (z==0) ? q16 : k16;
  const int mt = blockIdx.y, nt = blockIdx.x;
  const int tid = threadIdx.x;
  const int lane = tid & 63, wid = tid >> 6;
  const int wm = wid >> 1, wn = wid & 1;
  const int quad = lane >> 4, l16 = lane & 15;

  __shared__ __align__(16) f16 As[BM][LDA];
  __shared__ __align__(16) f16 Bs[BN][LDA];

  float4_ acc[4][4];
#pragma unroll
  for (int i=0;i<4;i++)
#pragma unroll
    for (int j=0;j<4;j++) acc[i][j] = (float4_)0.0f;

  const int row0 = mt*BM;
  const int col0 = nt*BN;

  for (int ko = 0; ko < D_; ko += BK) {
#pragma unroll
    for (int it=0; it<4; it++) {
      int c = it*256 + tid;
      int r = c >> 3, c8 = (c & 7)*8;
      *(half8*)&As[r][c8] = *(const half8*)&hs16[(size_t)(row0+r)*D_ + ko + c8];
      *(half8*)&Bs[r][c8] = *(const half8*)&W[(size_t)(col0+r)*D_ + ko + c8];
    }
    __syncthreads();
#pragma unroll
    for (int kk=0; kk<BK; kk+=32) {
      half8 a[4], b[4];
#pragma unroll
      for (int i=0;i<4;i++) a[i] = *(const half8*)&As[wm*64+i*16+l16][kk+quad*8];
#pragma unroll
      for (int j=0;j<4;j++) b[j] = *(const half8*)&Bs[wn*64+j*16+l16][kk+quad*8];
#pragma unroll
      for (int i=0;i<4;i++)
#pragma unroll
        for (int j=0;j<4;j++)
          acc[i][j] = __builtin_amdgcn_mfma_f32_16x16x32_f16(a[i], b[j], acc[i][j], 0,0,0);
    }
    __syncthreads();
  }
#pragma unroll
  for (int i=0;i<4;i++) {
#pragma unroll
    for (int j=0;j<4;j++) {
      int colg = col0 + wn*64 + j*16 + l16;
      float bias = (z==2) ? bv[colg] : 0.0f;
#pragma unroll
      for (int r=0;r<4;r++) {
        int rowg = row0 + wm*64 + i*16 + quad*4 + r;
        f16 val = (f16)(acc[i][j][r] + bias);
        if (z == 2) {
          int bb = rowg >> 11, ss = rowg & (S_-1);
          vT[((size_t)bb*D_ + colg)*S_ + ss] = val;
        } else {
          out[(size_t)rowg*D_ + colg] = val;
        }
      }
    }
  }
}

// ---------------- flash attention: per (b, h, 128-query tile), full S key loop ----------------
#define TQ 128
#define TK 128
#define LDP 136

__global__ __launch_bounds__(256, 2) void attn_kernel(
    const f16* __restrict__ q16, const f16* __restrict__ k16,
    const f16* __restrict__ vT, const f16* __restrict__ mix16,
    float* __restrict__ out)
{
  const int b = blockIdx.z;
  const int h = blockIdx.y;
  const int s0 = blockIdx.x * TQ;
  const int tid = threadIdx.x;
  const int lane = tid & 63, wid = tid >> 6;
  const int wm = wid >> 1, wn = wid & 1;
  const int quad = lane >> 4, l16 = lane & 15;

  // staging: q padded (VALU-written, mix fused), k UNPADDED xor-swizzled (DMA via global_load_lds)
  __shared__ __align__(16) union {
    struct { f16 q[TQ][LDA]; f16 k[TK*BK]; } s1;   // 18432 + 16384 = 34816 B
    f16 P[TQ][LDP];                                // 34816 B
  } u;
  __shared__ float red_m[2][TQ], red_s[2][TQ];

  // per-lane online-softmax state: 16 rows/lane (row = wm*64+i*16+quad*4+r)
  float m_reg[16], l_reg[16];
#pragma unroll
  for (int t=0;t<16;t++) { m_reg[t] = -1e30f; l_reg[t] = 0.0f; }

  float4_ o_acc[4][2];
#pragma unroll
  for (int i=0;i<4;i++)
#pragma unroll
    for (int j=0;j<2;j++) o_acc[i][j] = (float4_)0.0f;

  const f16* qbase = q16 + (size_t)(b*S_ + s0)*D_;
  const f16* kbase = k16 + (size_t)b*S_*D_;
  const f16* mrow  = mix16 + h*D_;
  const f16* vTb   = vT + (size_t)(b*D_ + h*HD_)*S_;

  for (int t0 = 0; t0 < S_; t0 += TK) {
    // ---- S = (q*mix) @ k^T over K=1024 ----
    float4_ sacc[4][4];
#pragma unroll
    for (int i=0;i<4;i++)
#pragma unroll
      for (int j=0;j<4;j++) sacc[i][j] = (float4_)0.0f;

    for (int ko = 0; ko < D_; ko += BK) {
      // k-tile DMA: wave wid stages slots (wid*4+c)*64 + lane; slot s -> row r=s>>3, store col cs=s&7,
      // global chunk gc = cs ^ (r&7)  (xor swizzle; 128B-line coalesced)
      const f16* kko = kbase + (size_t)t0*D_ + ko;
#pragma unroll
      for (int c=0; c<4; c++) {
        int slot = (wid*4+c)*64 + lane;
        int r = slot >> 3;
        int gc = (slot & 7) ^ (r & 7);
        gl_lds16(kko + (size_t)r*D_ + gc*8, u.s1.k + (size_t)(wid*4+c)*64*8);
      }
      // q-tile: VALU staging with mix fused, padded layout
#pragma unroll
      for (int it=0; it<4; it++) {
        int c = it*256 + tid;
        int r = c >> 3, c8 = (c & 7)*8;
        half8 qv = *(const half8*)&qbase[(size_t)r*D_ + ko + c8];
        half8 mv = *(const half8*)&mrow[ko + c8];
        *(half8*)&u.s1.q[r][c8] = qv * mv;
      }
      __syncthreads();
#pragma unroll
      for (int kk=0; kk<BK; kk+=32) {
        half8 a[4], bf[4];
#pragma unroll
        for (int i=0;i<4;i++) a[i]  = *(const half8*)&u.s1.q[wm*64+i*16+l16][kk+quad*8];
#pragma unroll
        for (int j=0;j<4;j++) {
          int rr = wn*64 + j*16 + l16;
          int ck = (kk >> 3) + quad;
          bf[j] = *(const half8*)&u.s1.k[(size_t)(((rr<<3) | (ck ^ (rr&7))) << 3)];
        }
#pragma unroll
        for (int i=0;i<4;i++)
#pragma unroll
          for (int j=0;j<4;j++)
            sacc[i][j] = __builtin_amdgcn_mfma_f32_16x16x32_f16(a[i], bf[j], sacc[i][j], 0,0,0);
      }
      __syncthreads();
    }

    // ---- row max (in-wave over l16, cross-wave via red_m) ----
    float rmax[16];
#pragma unroll
    for (int i=0;i<4;i++)
#pragma unroll
      for (int r=0;r<4;r++) {
        float v0 = fmaxf(sacc[i][0][r], sacc[i][1][r]);
        float v1 = fmaxf(sacc[i][2][r], sacc[i][3][r]);
        rmax[i*4+r] = fmaxf(v0, v1);
      }
#pragma unroll
    for (int d=1; d<16; d<<=1)
#pragma unroll
      for (int t=0;t<16;t++) rmax[t] = fmaxf(rmax[t], __shfl_xor(rmax[t], d));
    if (l16 == 0) {
#pragma unroll
      for (int i=0;i<4;i++)
#pragma unroll
        for (int r=0;r<4;r++)
          red_m[wn][wm*64+i*16+quad*4+r] = rmax[i*4+r];
    }
    __syncthreads();

    // ---- P = exp(S - m), rowsum; rescale O; all state per-lane ----
    float aloc[16], rsum[16];
#pragma unroll
    for (int i=0;i<4;i++)
#pragma unroll
      for (int r=0;r<4;r++) {
        int t = i*4+r;
        int row = wm*64+i*16+quad*4+r;
        float other = red_m[1-wn][row];
        float mnew = fmaxf(m_reg[t], fmaxf(rmax[t], other));
        aloc[t] = __expf(m_reg[t] - mnew);
        m_reg[t] = mnew;
        rsum[t] = 0.0f;
      }
#pragma unroll
    for (int i=0;i<4;i++)
#pragma unroll
      for (int j=0;j<4;j++)
#pragma unroll
        for (int r=0;r<4;r++) {
          float p = __expf(sacc[i][j][r] - m_reg[i*4+r]);
          rsum[i*4+r] += p;
          u.P[wm*64+i*16+quad*4+r][wn*64+j*16+l16] = (f16)p;
        }
#pragma unroll
    for (int d=1; d<16; d<<=1)
#pragma unroll
      for (int t=0;t<16;t++) rsum[t] += __shfl_xor(rsum[t], d);
    if (l16 == 0) {
#pragma unroll
      for (int i=0;i<4;i++)
#pragma unroll
        for (int r=0;r<4;r++)
          red_s[wn][wm*64+i*16+quad*4+r] = rsum[i*4+r];
    }
    // rescale O accumulators by alpha
#pragma unroll
    for (int i=0;i<4;i++)
#pragma unroll
      for (int j=0;j<2;j++)
#pragma unroll
        for (int r=0;r<4;r++) o_acc[i][j][r] *= aloc[i*4+r];

    // prefetch PV B-fragments from global vT (latency hides under barrier)
    half8 vb[8];
#pragma unroll
    for (int ki=0; ki<4; ki++)
#pragma unroll
      for (int j=0; j<2; j++) {
        int ch = wn*32 + j*16 + l16;
        vb[ki*2+j] = *(const half8*)&vTb[(size_t)ch*S_ + t0 + ki*32 + quad*8];
      }

    __syncthreads();
    // l update (per-lane; both waves read both halves -> consistent)
#pragma unroll
    for (int i=0;i<4;i++)
#pragma unroll
      for (int r=0;r<4;r++) {
        int t = i*4+r;
        int row = wm*64+i*16+quad*4+r;
        l_reg[t] = aloc[t]*l_reg[t] + red_s[0][row] + red_s[1][row];
      }

    // ---- O += P @ V ----
#pragma unroll
    for (int ki=0; ki<4; ki++) {
      half8 pa[4];
#pragma unroll
      for (int i=0;i<4;i++) pa[i] = *(const half8*)&u.P[wm*64+i*16+l16][ki*32+quad*8];
#pragma unroll
      for (int i=0;i<4;i++)
#pragma unroll
        for (int j=0;j<2;j++)
          o_acc[i][j] = __builtin_amdgcn_mfma_f32_16x16x32_f16(pa[i], vb[ki*2+j], o_acc[i][j], 0,0,0);
    }
    __syncthreads();
  }

  // ---- epilogue: normalized output ----
#pragma unroll
  for (int i=0;i<4;i++) {
#pragma unroll
    for (int j=0;j<2;j++) {
      int colg = h*HD_ + wn*32 + j*16 + l16;
#pragma unroll
      for (int r=0;r<4;r++) {
        int row = wm*64 + i*16 + quad*4 + r;
        float linv = 1.0f / l_reg[i*4+r];
        out[(size_t)(b*S_ + s0 + row)*D_ + colg] = o_acc[i][j][r] * linv;
      }
    }
  }
}

// ---------------- launch ----------------
extern "C" void kernel_launch(void* const* d_in, const int* in_sizes, int n_in,
                              void* d_out, int out_size, void* d_ws, size_t ws_size,
                              hipStream_t stream) {
  (void)in_sizes; (void)n_in; (void)out_size; (void)ws_size;
  const float* hs  = (const float*)d_in[0];
  const float* Wq  = (const float*)d_in[1];
  const float* Wk  = (const float*)d_in[2];
  const float* Wv  = (const float*)d_in[3];
  const float* bv  = (const float*)d_in[4];
  const float* mix = (const float*)d_in[5];
  float* out = (float*)d_out;

  char* ws = (char*)d_ws;
  f16* hs16  = (f16*)(ws);                       // 8 MB
  f16* w16   = (f16*)(ws + 8388608);             // 6 MB
  f16* mix16 = (f16*)(ws + 14680064);            // 32 KB
  f16* q16   = (f16*)(ws + 14712832);            // 8 MB
  f16* k16   = (f16*)(ws + 23101440);            // 8 MB
  f16* vT    = (f16*)(ws + 31490048);            // 8 MB

  convert_kernel<<<2048, 256, 0, stream>>>(hs, Wq, Wk, Wv, mix,
                                           hs16, w16, w16+N_W, w16+2*N_W, mix16);
  qkv_kernel<<<dim3(D_/BN, (B_*S_)/BM, 3), 256, 0, stream>>>(
      hs16, w16, bv, q16, k16, vT);
  attn_kernel<<<dim3(S_/TQ, H_, B_), 256, 0, stream>>>(
      q16, k16, vT, mix16, out);
}